// Round 6
// baseline (215.357 us; speedup 1.0000x reference)
//
#include <hip/hip_runtime.h>
#include <hip/hip_bf16.h>

#define NN 100000   // nodes
#define NE 200000   // edges
#define NG 2500     // graphs
#define FN 16       // node feats
#define FE 8        // edge feats
#define H1C 32
#define H2C 16
#define KH 16       // edge-MLP hidden

typedef __attribute__((ext_vector_type(8))) short short8;
typedef __attribute__((ext_vector_type(4))) float f32x4;
typedef _Float16 __attribute__((ext_vector_type(2))) half2v;
typedef _Float16 __attribute__((ext_vector_type(8))) half8v;
typedef __fp16 __attribute__((ext_vector_type(2))) pkf16x2;   // cvt_pkrtz result type

__device__ __forceinline__ float bf2f(unsigned int u){
  union { unsigned int i; float f; } v; v.i = (u & 0xffffu) << 16; return v.f;
}
__device__ __forceinline__ unsigned int pkh(float a, float b){
  union { pkf16x2 h; unsigned int u; } v; v.h = __builtin_amdgcn_cvt_pkrtz(a, b); return v.u;
}
__device__ __forceinline__ unsigned short f2h(float f){
  union { _Float16 h; unsigned short s; } v; v.h = (_Float16)f; return v.s;
}
__device__ __forceinline__ float h2lo(unsigned int u){
  union { unsigned short s; _Float16 h; } v; v.s = (unsigned short)u; return (float)v.h;
}
__device__ __forceinline__ float h2hi(unsigned int u){
  union { unsigned short s; _Float16 h; } v; v.s = (unsigned short)(u >> 16); return (float)v.h;
}
__device__ __forceinline__ float rdf(const void* p, long i, bool isbf){
  return isbf ? bf2f(((const unsigned short*)p)[i]) : ((const float*)p)[i];
}
// inline dtype detection: wave-ballot over 64 sampled halfwords of x
__device__ __forceinline__ bool detect_isbf(const void* __restrict__ x){
  const unsigned short* u = (const unsigned short*)x;
  int lane = threadIdx.x & 63;
  float f = bf2f(u[2*lane]);
  float a = fabsf(f);
  bool sane = (f == 0.0f) || (a > 1e-4f && a < 1e4f);
  unsigned long long b = __ballot(sane);
  return __popcll(b) >= 32;
}

#define NW 20
struct WArgs { const void* p[NW]; };
enum {
  OW_E1A=0,     OB_E1A=128,   OW_E1B=144,   OB_E1B=8336,  OW_R1=8848,  OB_R1=9360,
  OW_E2A=9392,  OB_E2A=9520,  OW_E2B=9536,  OB_E2B=17728, OW_R2=18240, OB_R2=18752,
  OW_G1=18768,  OB_G1=19024,  OW_G2=19040,  OB_G2=19056,
  OW_L1=19057,  OB_L1=19313,  OW_L2=19321,  OB_L2=19329
};

// ---- mega setup: wts-cvt | wpack1 | wpack2 | gate+cvt+gstart | edge-MLP+histogram ----
#define MB_A 76               // wts cvt: 19330 elems
#define MB_B (MB_A + 19)      // wpack1: 4736
#define MB_C (MB_B + 18)      // wpack2: 4416
#define MB_D (MB_C + 391)     // gate_cvt: NN
#define MB_E (MB_D + 782)     // edge-MLP + deg histogram: NE
__global__ void __launch_bounds__(256) mega1_kernel(
    const void* __restrict__ xin, const void* __restrict__ efin, WArgs w,
    const int* __restrict__ batch, const int* __restrict__ ei,
    float* __restrict__ wts, unsigned int* __restrict__ wpack1, unsigned int* __restrict__ wpack2,
    float* __restrict__ gate, float* __restrict__ xf,
    unsigned int* __restrict__ hpk1, unsigned int* __restrict__ hpk2,
    int* __restrict__ gstart, int* __restrict__ deg)
{
  int b = blockIdx.x, tid = threadIdx.x;
  if(b < MB_A){
    bool isbf = detect_isbf(xin);
    int i = b*256 + tid;
    if(i >= 19330) return;
    const int sz[NW] = {128,16,8192,512,512,32, 128,16,8192,512,512,16, 256,16,16,1, 256,8,8,1};
    int seg = 0; long base = 0;
    while(i - base >= sz[seg]){ base += sz[seg]; seg++; }
    wts[i] = rdf(w.p[seg], i - base, isbf);
    return;
  }
  if(b < MB_B){   // wpack1: 32 rows x 148 u32 (KP=296), round-7-verified layout, f16 payload
    bool isbf = detect_isbf(xin);
    int j = (b - MB_A)*256 + tid;
    if(j >= 4736) return;
    int n = j / 148; int k = (j % 148) * 2;
    float v0 = 0.f, v1 = 0.f;
    if(k < 256)        v0 = rdf(w.p[2], (long)k*32 + n, isbf);
    else if(k < 272)   v0 = rdf(w.p[3], (long)(k-256)*32 + n, isbf);
    if(k+1 < 256)      v1 = rdf(w.p[2], (long)(k+1)*32 + n, isbf);
    else if(k+1 < 272) v1 = rdf(w.p[3], (long)(k+1-256)*32 + n, isbf);
    wpack1[j] = pkh(v0, v1);
    return;
  }
  if(b < MB_C){   // wpack2: 16 rows x 276 u32 (KP=552), f16 payload
    bool isbf = detect_isbf(xin);
    int j = (b - MB_B)*256 + tid;
    if(j >= 4416) return;
    int n = j / 276; int k = (j % 276) * 2;
    float v0 = 0.f, v1 = 0.f;
    if(k < 512)        v0 = rdf(w.p[8], (long)k*16 + n, isbf);
    else if(k < 544)   v0 = rdf(w.p[9], (long)(k-512)*16 + n, isbf);
    if(k+1 < 512)      v1 = rdf(w.p[8], (long)(k+1)*16 + n, isbf);
    else if(k+1 < 544) v1 = rdf(w.p[9], (long)(k+1-512)*16 + n, isbf);
    wpack2[j] = pkh(v0, v1);
    return;
  }
  if(b < MB_D){   // gate MLP + x conversion + gstart table (one pass over raw x)
    __shared__ float s_w1[FN*FN], s_b1[FN], s_w2[FN], s_b2v[1];
    bool isbf = detect_isbf(xin);
    if(tid < FN*FN) s_w1[tid] = rdf(w.p[12], tid, isbf);
    if(tid < FN){ s_b1[tid] = rdf(w.p[13], tid, isbf); s_w2[tid] = rdf(w.p[14], tid, isbf); }
    if(tid == 0) s_b2v[0] = rdf(w.p[15], 0, isbf);
    __syncthreads();
    int n = (b - MB_C)*256 + tid;
    if(n >= NN) return;
    {
      int b1 = batch[n];
      int b0 = (n == 0) ? -1 : batch[n-1];
      for(int g2 = b0 + 1; g2 <= b1; g2++) gstart[g2] = n;
      if(n == NN-1) for(int g2 = b1 + 1; g2 <= NG; g2++) gstart[g2] = NN;
    }
    float xv[FN];
    if(isbf){
      uint4 u0 = ((const uint4*)xin)[2*n], u1 = ((const uint4*)xin)[2*n+1];
      xv[0]=bf2f(u0.x); xv[1]=bf2f(u0.x>>16); xv[2]=bf2f(u0.y); xv[3]=bf2f(u0.y>>16);
      xv[4]=bf2f(u0.z); xv[5]=bf2f(u0.z>>16); xv[6]=bf2f(u0.w); xv[7]=bf2f(u0.w>>16);
      xv[8]=bf2f(u1.x); xv[9]=bf2f(u1.x>>16); xv[10]=bf2f(u1.y); xv[11]=bf2f(u1.y>>16);
      xv[12]=bf2f(u1.z); xv[13]=bf2f(u1.z>>16); xv[14]=bf2f(u1.w); xv[15]=bf2f(u1.w>>16);
    } else {
      #pragma unroll
      for(int q = 0; q < 4; q++){
        float4 v = ((const float4*)xin)[4*n + q];
        xv[q*4+0]=v.x; xv[q*4+1]=v.y; xv[q*4+2]=v.z; xv[q*4+3]=v.w;
      }
    }
    float4* xo = (float4*)(xf + (size_t)n*FN);
    #pragma unroll
    for(int q = 0; q < 4; q++) xo[q] = make_float4(xv[q*4+0], xv[q*4+1], xv[q*4+2], xv[q*4+3]);
    float g = s_b2v[0];
    #pragma unroll
    for(int j = 0; j < FN; j++){
      float hj = s_b1[j];
      #pragma unroll
      for(int i = 0; i < FN; i++) hj += xv[i] * s_w1[i*FN + j];
      hj = hj > 0.f ? hj : 0.f;
      g += hj * s_w2[j];
    }
    gate[n] = g;
    return;
  }
  {   // edge-MLP (original order, coalesced) + target-degree histogram
    __shared__ float s_w1[FE*KH], s_b1[KH], s_w2[FE*KH], s_b2[KH];
    bool isbf = detect_isbf(xin);
    if(tid < FE*KH){ s_w1[tid] = rdf(w.p[0], tid, isbf); s_w2[tid] = rdf(w.p[6], tid, isbf); }
    if(tid < KH){ s_b1[tid] = rdf(w.p[1], tid, isbf); s_b2[tid] = rdf(w.p[7], tid, isbf); }
    __syncthreads();
    int e = (b - MB_D)*256 + tid;
    if(e >= NE) return;
    atomicAdd(&deg[ei[NE + e]], 1);
    float ev[FE];
    if(isbf){
      uint4 u = ((const uint4*)efin)[e];
      ev[0]=bf2f(u.x); ev[1]=bf2f(u.x>>16); ev[2]=bf2f(u.y); ev[3]=bf2f(u.y>>16);
      ev[4]=bf2f(u.z); ev[5]=bf2f(u.z>>16); ev[6]=bf2f(u.w); ev[7]=bf2f(u.w>>16);
    } else {
      float4 a = ((const float4*)efin)[2*e], bb = ((const float4*)efin)[2*e+1];
      ev[0]=a.x; ev[1]=a.y; ev[2]=a.z; ev[3]=a.w; ev[4]=bb.x; ev[5]=bb.y; ev[6]=bb.z; ev[7]=bb.w;
    }
    unsigned int o[8];
    #pragma unroll
    for(int d = 0; d < 8; d++){
      float h0 = s_b1[2*d], h1 = s_b1[2*d+1];
      #pragma unroll
      for(int k = 0; k < FE; k++){
        h0 += ev[k] * s_w1[k*KH + 2*d];
        h1 += ev[k] * s_w1[k*KH + 2*d+1];
      }
      h0 = h0 > 0.f ? h0 : 0.f; h1 = h1 > 0.f ? h1 : 0.f;
      o[d] = pkh(h0, h1);
    }
    uint4* p1 = (uint4*)(hpk1 + (size_t)e*8);
    p1[0] = make_uint4(o[0],o[1],o[2],o[3]); p1[1] = make_uint4(o[4],o[5],o[6],o[7]);
    #pragma unroll
    for(int d = 0; d < 8; d++){
      float h0 = s_b2[2*d], h1 = s_b2[2*d+1];
      #pragma unroll
      for(int k = 0; k < FE; k++){
        h0 += ev[k] * s_w2[k*KH + 2*d];
        h1 += ev[k] * s_w2[k*KH + 2*d+1];
      }
      h0 = h0 > 0.f ? h0 : 0.f; h1 = h1 > 0.f ? h1 : 0.f;
      o[d] = pkh(h0, h1);
    }
    uint4* p2 = (uint4*)(hpk2 + (size_t)e*8);
    p2[0] = make_uint4(o[0],o[1],o[2],o[3]); p2[1] = make_uint4(o[4],o[5],o[6],o[7]);
  }
}

// ---- single-launch exclusive scan (R0-proven): publish aggregate, parallel poll ----
#define SCAN_NB 98
__global__ void __launch_bounds__(256) scan_kernel(
    const int* __restrict__ deg, int* __restrict__ rowptr, int* __restrict__ cursor,
    unsigned int* __restrict__ pub)
{
  __shared__ int s_thr[256];
  __shared__ int s_agg[SCAN_NB];
  __shared__ int s_bcast;
  int tid = threadIdx.x, bid = blockIdx.x;
  int base = bid*1024 + tid*4;
  int v0=0, v1=0, v2=0, v3=0;
  if(base + 3 < NN){
    int4 t4 = *(const int4*)(deg + base);
    v0=t4.x; v1=t4.y; v2=t4.z; v3=t4.w;
  } else {
    if(base+0 < NN) v0 = deg[base+0];
    if(base+1 < NN) v1 = deg[base+1];
    if(base+2 < NN) v2 = deg[base+2];
  }
  int e1 = v0, e2 = v0+v1, e3 = v0+v1+v2, tot = v0+v1+v2+v3;
  s_thr[tid] = tot;
  __syncthreads();
  for(int off = 1; off < 256; off <<= 1){
    int t = (tid >= off) ? s_thr[tid-off] : 0;
    __syncthreads();
    s_thr[tid] += t;
    __syncthreads();
  }
  int thr_excl = s_thr[tid] - tot;
  int agg = s_thr[255];
  if(tid == 0) atomicExch(&pub[bid], ((unsigned int)agg << 1) | 1u);
  if(tid < SCAN_NB){
    unsigned int v;
    do { v = atomicAdd(&pub[tid], 0u); } while((v & 1u) == 0u);
    s_agg[tid] = (int)(v >> 1);
  }
  __syncthreads();
  if(tid == 0){
    int acc = 0;
    for(int p = 0; p < bid; p++) acc += s_agg[p];
    s_bcast = acc;
  }
  __syncthreads();
  int ex = s_bcast + thr_excl;
  if(base + 3 < NN){
    int4 r = make_int4(ex, ex+e1, ex+e2, ex+e3);
    *(int4*)(rowptr + base) = r;
    *(int4*)(cursor + base) = r;
  } else {
    if(base+0 < NN){ rowptr[base+0]=ex;    cursor[base+0]=ex;    }
    if(base+1 < NN){ rowptr[base+1]=ex+e1; cursor[base+1]=ex+e1; }
    if(base+2 < NN){ rowptr[base+2]=ex+e2; cursor[base+2]=ex+e2; }
  }
  if(bid == 0 && tid == 0) rowptr[NN] = NE;
}

// ---- NNConv message GEMM, ORIGINAL edge order, coalesced msg writes (no atomics) ----
// FILL=true: extra trailing blocks build the eidx permutation (independent work).
#define CONV_NB (NE/64)       // 3125
#define FILL_NB 782
template<int IN, int OUT, bool AH, bool FILL>
__global__ void __launch_bounds__(256) conv_msg_kernel(
    const void* __restrict__ nodef, const unsigned int* __restrict__ hpk,
    const int* __restrict__ ei, int* __restrict__ cursor, int* __restrict__ eidx,
    const unsigned short* __restrict__ wpack, unsigned short* __restrict__ msg)
{
  if(FILL && blockIdx.x >= CONV_NB){
    int e = (blockIdx.x - CONV_NB)*256 + threadIdx.x;
    if(e < NE){
      int pos = atomicAdd(&cursor[ei[NE + e]], 1);
      eidx[pos] = e;
    }
    return;
  }
  constexpr int KMF  = ((KH*IN + IN + 31)/32)*32;   // 288 | 544
  constexpr int KP   = KMF + 8;                     // 296 | 552
  constexpr int NT   = OUT/16;                      // 2 | 1
  constexpr int KS   = KMF/32;                      // 9 | 17
  int tid = threadIdx.x;
  int lane = tid & 63, m = lane & 15, quad = lane >> 4;
  int wid = tid >> 6;
  int ebase = blockIdx.x*64 + wid*16;
  int em = ebase + m;
  int sn = ei[em];                                  // src node
  int q1 = quad >> 1;
  int xoff = (IN == 16) ? ((quad & 1)*8) : (quad*8);
  union { half8v v; half2v h[4]; unsigned int w[4]; } X;
  if(AH){
    uint4 u = *(const uint4*)((const unsigned short*)nodef + (size_t)sn*IN + xoff);
    X.w[0]=u.x; X.w[1]=u.y; X.w[2]=u.z; X.w[3]=u.w;
  } else {
    const float4* xp = (const float4*)((const float*)nodef + (size_t)sn*IN + xoff);
    float4 v0 = xp[0], v1 = xp[1];
    X.w[0] = pkh(v0.x, v0.y);
    X.w[1] = pkh(v0.z, v0.w);
    X.w[2] = pkh(v1.x, v1.y);
    X.w[3] = pkh(v1.z, v1.w);
  }
  unsigned int hu[8];
  {
    const uint4* hp = (const uint4*)(hpk + (size_t)em*8);
    uint4 u0 = hp[0], u1 = hp[1];
    hu[0]=u0.x; hu[1]=u0.y; hu[2]=u0.z; hu[3]=u0.w;
    hu[4]=u1.x; hu[5]=u1.y; hu[6]=u1.z; hu[7]=u1.w;
  }

  f32x4 acc[NT];
  #pragma unroll
  for(int nt = 0; nt < NT; nt++) acc[nt] = (f32x4){0.f,0.f,0.f,0.f};

  const half8v hz = {};
  #pragma unroll
  for(int ks = 0; ks < KS; ks++){
    union { half8v v; half2v h[4]; } A;
    if(ks < KS-1){
      unsigned short hs = (unsigned short)((IN == 16) ? (hu[ks] >> (16*q1))
                                                      : (hu[ks >> 1] >> (16*(ks & 1))));
      union { unsigned short s; _Float16 h; } hc; hc.s = hs;
      half2v hv2 = { hc.h, hc.h };
      #pragma unroll
      for(int k = 0; k < 4; k++) A.h[k] = hv2 * X.h[k];   // v_pk_mul_f16
    } else {
      if(IN == 16) A.v = (quad < 2) ? X.v : hz;
      else         A.v = X.v;
    }
    #pragma unroll
    for(int nt = 0; nt < NT; nt++){
      half8v b = *(const half8v*)(wpack + (size_t)(nt*16 + m)*KP + ks*32 + quad*8);
      acc[nt] = __builtin_amdgcn_mfma_f32_16x16x32_f16(A.v, b, acc[nt], 0, 0, 0);
    }
  }
  #pragma unroll
  for(int nt = 0; nt < NT; nt++)
    #pragma unroll
    for(int r = 0; r < 4; r++)   // C layout: row=(lane>>4)*4+reg (edge), col=lane&15
      msg[(size_t)(ebase + quad*4 + r)*OUT + nt*16 + m] = f2h(acc[nt][r]);
}

// h1 = relu(x@wr1 + br1 + sum_{j in CSR row} msg1[eidx[j]]) -> f16. 8 threads/node.
__global__ void __launch_bounds__(256) node1_kernel(
    const float* __restrict__ xf, const unsigned short* __restrict__ msg,
    const int* __restrict__ rowptr, const int* __restrict__ eidx,
    const float* __restrict__ wr, const float* __restrict__ br,
    unsigned short* __restrict__ h1b)
{
  __shared__ float s_w[FN*H1C], s_b[H1C];
  for(int i = threadIdx.x; i < FN*H1C; i += 256) s_w[i] = wr[i];
  if(threadIdx.x < H1C) s_b[threadIdx.x] = br[threadIdx.x];
  __syncthreads();
  int g = blockIdx.x*256 + threadIdx.x;
  int n = g >> 3, q = g & 7;
  if(n >= NN) return;
  float a0 = s_b[q*4+0], a1 = s_b[q*4+1], a2 = s_b[q*4+2], a3 = s_b[q*4+3];
  int jb = rowptr[n], je = rowptr[n+1];
  for(int j = jb; j < je; j++){
    int e = eidx[j];
    const unsigned int* mp = (const unsigned int*)(msg + (size_t)e*H1C + q*4);
    unsigned int u0 = mp[0], u1 = mp[1];
    a0 += h2lo(u0); a1 += h2hi(u0); a2 += h2lo(u1); a3 += h2hi(u1);
  }
  const float* xr = xf + (size_t)n*FN;
  #pragma unroll
  for(int i = 0; i < FN; i++){
    float xi = xr[i];
    a0 += xi*s_w[i*H1C + q*4+0]; a1 += xi*s_w[i*H1C + q*4+1];
    a2 += xi*s_w[i*H1C + q*4+2]; a3 += xi*s_w[i*H1C + q*4+3];
  }
  a0 = a0>0.f?a0:0.f; a1 = a1>0.f?a1:0.f; a2 = a2>0.f?a2:0.f; a3 = a3>0.f?a3:0.f;
  uint2 hb; hb.x = pkh(a0, a1); hb.y = pkh(a2, a3);
  *(uint2*)(h1b + (size_t)n*H1C + q*4) = hb;
}

// h2 = relu(h1@wr2 + br2 + sum msg2[eidx[j]]); 4 threads/node; h1 read as f16
__global__ void __launch_bounds__(256) node2_kernel(
    const unsigned short* __restrict__ h1b, const unsigned short* __restrict__ msg,
    const int* __restrict__ rowptr, const int* __restrict__ eidx,
    const float* __restrict__ wr, const float* __restrict__ br, float* __restrict__ h2)
{
  __shared__ float s_w[H1C*H2C], s_b[H2C];
  for(int i = threadIdx.x; i < H1C*H2C; i += 256) s_w[i] = wr[i];
  if(threadIdx.x < H2C) s_b[threadIdx.x] = br[threadIdx.x];
  __syncthreads();
  int g = blockIdx.x*256 + threadIdx.x;
  int n = g >> 2, q = g & 3;
  if(n >= NN) return;
  float a0 = s_b[q*4+0], a1 = s_b[q*4+1], a2 = s_b[q*4+2], a3 = s_b[q*4+3];
  int jb = rowptr[n], je = rowptr[n+1];
  for(int j = jb; j < je; j++){
    int e = eidx[j];
    const unsigned int* mp = (const unsigned int*)(msg + (size_t)e*H2C + q*4);
    unsigned int u0 = mp[0], u1 = mp[1];
    a0 += h2lo(u0); a1 += h2hi(u0); a2 += h2lo(u1); a3 += h2hi(u1);
  }
  const unsigned int* hb = (const unsigned int*)(h1b + (size_t)n*H1C);
  #pragma unroll
  for(int i2 = 0; i2 < H1C/2; i2++){
    unsigned int u = hb[i2];
    float x0 = h2lo(u), x1 = h2hi(u);
    int i = 2*i2;
    a0 += x0*s_w[i*H2C + q*4+0] + x1*s_w[(i+1)*H2C + q*4+0];
    a1 += x0*s_w[i*H2C + q*4+1] + x1*s_w[(i+1)*H2C + q*4+1];
    a2 += x0*s_w[i*H2C + q*4+2] + x1*s_w[(i+1)*H2C + q*4+2];
    a3 += x0*s_w[i*H2C + q*4+3] + x1*s_w[(i+1)*H2C + q*4+3];
  }
  float4 r; r.x = a0>0.f?a0:0.f; r.y = a1>0.f?a1:0.f; r.z = a2>0.f?a2:0.f; r.w = a3>0.f?a3:0.f;
  *(float4*)(h2 + (size_t)n*H2C + q*4) = r;
}

// one wave per graph: attention pool + mean-pool h2 + head MLP (gstart table)
__global__ void head_kernel(const float* __restrict__ gate, const float* __restrict__ xf,
    const float* __restrict__ h2, const int* __restrict__ gstart, const void* __restrict__ xin,
    const float* __restrict__ wl1, const float* __restrict__ bl1,
    const float* __restrict__ wl2, const float* __restrict__ bl2,
    void* __restrict__ out)
{
  __shared__ float sz[H2C + FN];
  int g = blockIdx.x;
  int lane = threadIdx.x;
  bool isbf = detect_isbf(xin);
  int start = gstart[g];
  int end   = gstart[g + 1];
  float m = -1e30f;
  for(int n = start + lane; n < end; n += 64) m = fmaxf(m, gate[n]);
  #pragma unroll
  for(int o = 32; o >= 1; o >>= 1) m = fmaxf(m, __shfl_xor(m, o));
  float s = 0.f;
  float acc[FN];
  #pragma unroll
  for(int f = 0; f < FN; f++) acc[f] = 0.f;
  for(int n = start + lane; n < end; n += 64){
    float a = __expf(gate[n] - m);
    s += a;
    const float4* xp = (const float4*)(xf + (size_t)n * FN);
    #pragma unroll
    for(int q = 0; q < 4; q++){
      float4 v = xp[q];
      acc[q*4+0] += a*v.x; acc[q*4+1] += a*v.y; acc[q*4+2] += a*v.z; acc[q*4+3] += a*v.w;
    }
  }
  #pragma unroll
  for(int o = 32; o >= 1; o >>= 1){
    s += __shfl_xor(s, o);
    #pragma unroll
    for(int f = 0; f < FN; f++) acc[f] += __shfl_xor(acc[f], o);
  }
  if(lane < FN) sz[H2C + lane] = (end > start && s > 0.f) ? acc[lane] / s : 0.f;
  #pragma unroll
  for(int f = 0; f < H2C; f++) acc[f] = 0.f;
  for(int n = start + lane; n < end; n += 64){
    const float4* hp = (const float4*)(h2 + (size_t)n*H2C);
    #pragma unroll
    for(int q = 0; q < 4; q++){
      float4 v = hp[q];
      acc[q*4+0] += v.x; acc[q*4+1] += v.y; acc[q*4+2] += v.z; acc[q*4+3] += v.w;
    }
  }
  #pragma unroll
  for(int o = 32; o >= 1; o >>= 1){
    #pragma unroll
    for(int f = 0; f < H2C; f++) acc[f] += __shfl_xor(acc[f], o);
  }
  float inv = 1.f / fmaxf((float)(end - start), 1.f);
  if(lane < H2C) sz[lane] = acc[lane] * inv;
  __syncthreads();
  if(lane == 0){
    float t1[8];
    #pragma unroll
    for(int j = 0; j < 8; j++){
      float t = bl1[j];
      #pragma unroll
      for(int c = 0; c < H2C + FN; c++) t += sz[c] * wl1[c*8 + j];
      t1[j] = t;
    }
    float o = bl2[0];
    #pragma unroll
    for(int j = 0; j < 8; j++) o += t1[j] * wl2[j];
    if(isbf) ((__hip_bfloat16*)out)[g] = __float2bfloat16(o);
    else     ((float*)out)[g] = o;
  }
}

extern "C" void kernel_launch(void* const* d_in, const int* in_sizes, int n_in,
                              void* d_out, int out_size, void* d_ws, size_t ws_size,
                              hipStream_t stream)
{
  const int* ei    = (const int*)d_in[22];
  const int* batch = (const int*)d_in[23];

  float* ws = (float*)d_ws;
  float* xf     = ws;                          // 1,600,000 f
  float* gate   = xf + 1600000;                //   100,000 f
  float* wts    = gate + 100000;               //    19,360 f
  int*   gstart = (int*)(wts + 19360);         //     2,504 i
  int*   deg    = gstart + 2504;               //   100,000 i
  int*   rowptr = deg + 100000;                //   100,016 i
  int*   cursor = rowptr + 100016;             //   100,000 i
  unsigned int* pub = (unsigned int*)(cursor + 100000);  // 256 u32
  int*   eidx   = (int*)(pub + 256);           //   200,000 i
  unsigned int* wpack1 = (unsigned int*)(eidx + 200000);   // 4,736 u32
  unsigned int* wpack2 = wpack1 + 4736;                    // 4,416 u32
  unsigned int* hpk1   = wpack2 + 4416;        // 1,600,000 u32 ([NE][8])
  unsigned int* hpk2   = hpk1 + 1600000;       // 1,600,000 u32
  unsigned short* h1b  = (unsigned short*)(hpk2 + 1600000); // 3,200,000 u16
  unsigned short* msg1 = h1b + 3200000;        // 6,400,000 u16 (12.8 MB)
  unsigned short* msg2 = msg1 + 6400000;       // 3,200,000 u16 (6.4 MB)
  float* h2     = (float*)(msg2 + 3200000);    // 1,600,000 f
  // total ~54 MB

  WArgs wa;
  for(int i = 0; i < NW; i++) wa.p[i] = d_in[2 + i];

  hipMemsetAsync(deg, 0, (100000 + 0)*sizeof(int), stream);
  hipMemsetAsync(pub, 0, 256*sizeof(unsigned int), stream);
  mega1_kernel<<<MB_E, 256, 0, stream>>>(d_in[0], d_in[1], wa, batch, ei,
      wts, wpack1, wpack2, gate, xf, hpk1, hpk2, gstart, deg);
  scan_kernel<<<SCAN_NB, 256, 0, stream>>>(deg, rowptr, cursor, pub);

  conv_msg_kernel<FN, H1C, false, true><<<CONV_NB + FILL_NB, 256, 0, stream>>>(
      xf, hpk1, ei, cursor, eidx, (const unsigned short*)wpack1, msg1);
  node1_kernel<<<(NN*8 + 255)/256, 256, 0, stream>>>(xf, msg1, rowptr, eidx,
      wts+OW_R1, wts+OB_R1, h1b);

  conv_msg_kernel<H1C, H2C, true, false><<<CONV_NB, 256, 0, stream>>>(
      h1b, hpk2, ei, cursor, eidx, (const unsigned short*)wpack2, msg2);
  node2_kernel<<<(NN*4 + 255)/256, 256, 0, stream>>>(h1b, msg2, rowptr, eidx,
      wts+OW_R2, wts+OB_R2, h2);

  head_kernel<<<NG, 64, 0, stream>>>(gate, xf, h2, gstart, d_in[0],
      wts+OW_L1, wts+OB_L1, wts+OW_L2, wts+OB_L2, d_out);
}

// Round 8
// 186.830 us; speedup vs baseline: 1.1527x; 1.1527x over previous
//
#include <hip/hip_runtime.h>
#include <hip/hip_bf16.h>

#define NN 100000   // nodes
#define NE 200000   // edges
#define NG 2500     // graphs
#define FN 16       // node feats
#define FE 8        // edge feats
#define H1C 32
#define H2C 16
#define KH 16       // edge-MLP hidden

typedef __attribute__((ext_vector_type(4))) float f32x4;
typedef _Float16 __attribute__((ext_vector_type(2))) half2v;
typedef _Float16 __attribute__((ext_vector_type(8))) half8v;
typedef __fp16 __attribute__((ext_vector_type(2))) pkf16x2;   // cvt_pkrtz result type

__device__ __forceinline__ float bf2f(unsigned int u){
  union { unsigned int i; float f; } v; v.i = (u & 0xffffu) << 16; return v.f;
}
__device__ __forceinline__ unsigned int pkh(float a, float b){
  union { pkf16x2 h; unsigned int u; } v; v.h = __builtin_amdgcn_cvt_pkrtz(a, b); return v.u;
}
__device__ __forceinline__ float h2lo(unsigned int u){
  union { unsigned short s; _Float16 h; } v; v.s = (unsigned short)u; return (float)v.h;
}
__device__ __forceinline__ float h2hi(unsigned int u){
  union { unsigned short s; _Float16 h; } v; v.s = (unsigned short)(u >> 16); return (float)v.h;
}
__device__ __forceinline__ float rdf(const void* p, long i, bool isbf){
  return isbf ? bf2f(((const unsigned short*)p)[i]) : ((const float*)p)[i];
}
// fire-and-forget packed-f16 atomic add (2 values / op)
__device__ __forceinline__ void atomic_pk_f16(unsigned short* addr, unsigned int pk){
  asm volatile("global_atomic_pk_add_f16 %0, %1, off" :: "v"(addr), "v"(pk) : "memory");
}
// inline dtype detection: wave-ballot over 64 sampled halfwords of x
__device__ __forceinline__ bool detect_isbf(const void* __restrict__ x){
  const unsigned short* u = (const unsigned short*)x;
  int lane = threadIdx.x & 63;
  float f = bf2f(u[2*lane]);
  float a = fabsf(f);
  bool sane = (f == 0.0f) || (a > 1e-4f && a < 1e4f);
  unsigned long long b = __ballot(sane);
  return __popcll(b) >= 32;
}

#define NW 20
struct WArgs { const void* p[NW]; };
enum {
  OW_E1A=0,     OB_E1A=128,   OW_E1B=144,   OB_E1B=8336,  OW_R1=8848,  OB_R1=9360,
  OW_E2A=9392,  OB_E2A=9520,  OW_E2B=9536,  OB_E2B=17728, OW_R2=18240, OB_R2=18752,
  OW_G1=18768,  OB_G1=19024,  OW_G2=19040,  OB_G2=19056,
  OW_L1=19057,  OB_L1=19313,  OW_L2=19321,  OB_L2=19329
};

// ---- mega setup: wts-cvt | wpack1 | wpack2 | gate+cvt+gstart | edge-MLP | agg-zero ----
#define MB_A 76               // wts cvt: 19330 elems
#define MB_B (MB_A + 19)      // wpack1: 4736
#define MB_C (MB_B + 18)      // wpack2: 4416
#define MB_D (MB_C + 391)     // gate_cvt: NN
#define MB_E (MB_D + 782)     // edge-MLP: NE (original order, coalesced writes)
#define MB_F (MB_E + 586)     // agg zero: 150000 x 64B
__global__ void __launch_bounds__(256) mega1_kernel(
    const void* __restrict__ xin, const void* __restrict__ efin, WArgs w,
    const int* __restrict__ batch,
    float* __restrict__ wts, unsigned int* __restrict__ wpack1, unsigned int* __restrict__ wpack2,
    float* __restrict__ gate, float* __restrict__ xf,
    unsigned int* __restrict__ hpk1, unsigned int* __restrict__ hpk2,
    int* __restrict__ gstart, unsigned short* __restrict__ agg1)
{
  int b = blockIdx.x, tid = threadIdx.x;
  if(b < MB_A){
    bool isbf = detect_isbf(xin);
    int i = b*256 + tid;
    if(i >= 19330) return;
    const int sz[NW] = {128,16,8192,512,512,32, 128,16,8192,512,512,16, 256,16,16,1, 256,8,8,1};
    int seg = 0; long base = 0;
    while(i - base >= sz[seg]){ base += sz[seg]; seg++; }
    wts[i] = rdf(w.p[seg], i - base, isbf);
    return;
  }
  if(b < MB_B){   // wpack1: 32 rows x 148 u32 (KP=296), f16 payload
    bool isbf = detect_isbf(xin);
    int j = (b - MB_A)*256 + tid;
    if(j >= 4736) return;
    int n = j / 148; int k = (j % 148) * 2;
    float v0 = 0.f, v1 = 0.f;
    if(k < 256)        v0 = rdf(w.p[2], (long)k*32 + n, isbf);
    else if(k < 272)   v0 = rdf(w.p[3], (long)(k-256)*32 + n, isbf);
    if(k+1 < 256)      v1 = rdf(w.p[2], (long)(k+1)*32 + n, isbf);
    else if(k+1 < 272) v1 = rdf(w.p[3], (long)(k+1-256)*32 + n, isbf);
    wpack1[j] = pkh(v0, v1);
    return;
  }
  if(b < MB_C){   // wpack2: 16 rows x 276 u32 (KP=552), f16 payload
    bool isbf = detect_isbf(xin);
    int j = (b - MB_B)*256 + tid;
    if(j >= 4416) return;
    int n = j / 276; int k = (j % 276) * 2;
    float v0 = 0.f, v1 = 0.f;
    if(k < 512)        v0 = rdf(w.p[8], (long)k*16 + n, isbf);
    else if(k < 544)   v0 = rdf(w.p[9], (long)(k-512)*16 + n, isbf);
    if(k+1 < 512)      v1 = rdf(w.p[8], (long)(k+1)*16 + n, isbf);
    else if(k+1 < 544) v1 = rdf(w.p[9], (long)(k+1-512)*16 + n, isbf);
    wpack2[j] = pkh(v0, v1);
    return;
  }
  if(b < MB_D){   // gate MLP + x conversion + gstart table (one pass over raw x)
    __shared__ float s_w1[FN*FN], s_b1[FN], s_w2[FN], s_b2v[1];
    bool isbf = detect_isbf(xin);
    if(tid < FN*FN) s_w1[tid] = rdf(w.p[12], tid, isbf);
    if(tid < FN){ s_b1[tid] = rdf(w.p[13], tid, isbf); s_w2[tid] = rdf(w.p[14], tid, isbf); }
    if(tid == 0) s_b2v[0] = rdf(w.p[15], 0, isbf);
    __syncthreads();
    int n = (b - MB_C)*256 + tid;
    if(n >= NN) return;
    {
      int b1 = batch[n];
      int b0 = (n == 0) ? -1 : batch[n-1];
      for(int g2 = b0 + 1; g2 <= b1; g2++) gstart[g2] = n;
      if(n == NN-1) for(int g2 = b1 + 1; g2 <= NG; g2++) gstart[g2] = NN;
    }
    float xv[FN];
    if(isbf){
      uint4 u0 = ((const uint4*)xin)[2*n], u1 = ((const uint4*)xin)[2*n+1];
      xv[0]=bf2f(u0.x); xv[1]=bf2f(u0.x>>16); xv[2]=bf2f(u0.y); xv[3]=bf2f(u0.y>>16);
      xv[4]=bf2f(u0.z); xv[5]=bf2f(u0.z>>16); xv[6]=bf2f(u0.w); xv[7]=bf2f(u0.w>>16);
      xv[8]=bf2f(u1.x); xv[9]=bf2f(u1.x>>16); xv[10]=bf2f(u1.y); xv[11]=bf2f(u1.y>>16);
      xv[12]=bf2f(u1.z); xv[13]=bf2f(u1.z>>16); xv[14]=bf2f(u1.w); xv[15]=bf2f(u1.w>>16);
    } else {
      #pragma unroll
      for(int q = 0; q < 4; q++){
        float4 v = ((const float4*)xin)[4*n + q];
        xv[q*4+0]=v.x; xv[q*4+1]=v.y; xv[q*4+2]=v.z; xv[q*4+3]=v.w;
      }
    }
    float4* xo = (float4*)(xf + (size_t)n*FN);
    #pragma unroll
    for(int q = 0; q < 4; q++) xo[q] = make_float4(xv[q*4+0], xv[q*4+1], xv[q*4+2], xv[q*4+3]);
    float g = s_b2v[0];
    #pragma unroll
    for(int j = 0; j < FN; j++){
      float hj = s_b1[j];
      #pragma unroll
      for(int i = 0; i < FN; i++) hj += xv[i] * s_w1[i*FN + j];
      hj = hj > 0.f ? hj : 0.f;
      g += hj * s_w2[j];
    }
    gate[n] = g;
    return;
  }
  if(b < MB_E){   // edge-MLP: per-edge h1,h2 hidden vectors, f16-packed, original order
    __shared__ float s_w1[FE*KH], s_b1[KH], s_w2[FE*KH], s_b2[KH];
    bool isbf = detect_isbf(xin);
    if(tid < FE*KH){ s_w1[tid] = rdf(w.p[0], tid, isbf); s_w2[tid] = rdf(w.p[6], tid, isbf); }
    if(tid < KH){ s_b1[tid] = rdf(w.p[1], tid, isbf); s_b2[tid] = rdf(w.p[7], tid, isbf); }
    __syncthreads();
    int e = (b - MB_D)*256 + tid;
    if(e >= NE) return;
    float ev[FE];
    if(isbf){
      uint4 u = ((const uint4*)efin)[e];
      ev[0]=bf2f(u.x); ev[1]=bf2f(u.x>>16); ev[2]=bf2f(u.y); ev[3]=bf2f(u.y>>16);
      ev[4]=bf2f(u.z); ev[5]=bf2f(u.z>>16); ev[6]=bf2f(u.w); ev[7]=bf2f(u.w>>16);
    } else {
      float4 a = ((const float4*)efin)[2*e], bb = ((const float4*)efin)[2*e+1];
      ev[0]=a.x; ev[1]=a.y; ev[2]=a.z; ev[3]=a.w; ev[4]=bb.x; ev[5]=bb.y; ev[6]=bb.z; ev[7]=bb.w;
    }
    unsigned int o[8];
    #pragma unroll
    for(int d = 0; d < 8; d++){
      float h0 = s_b1[2*d], h1 = s_b1[2*d+1];
      #pragma unroll
      for(int k = 0; k < FE; k++){
        h0 += ev[k] * s_w1[k*KH + 2*d];
        h1 += ev[k] * s_w1[k*KH + 2*d+1];
      }
      h0 = h0 > 0.f ? h0 : 0.f; h1 = h1 > 0.f ? h1 : 0.f;
      o[d] = pkh(h0, h1);
    }
    uint4* p1 = (uint4*)(hpk1 + (size_t)e*8);
    p1[0] = make_uint4(o[0],o[1],o[2],o[3]); p1[1] = make_uint4(o[4],o[5],o[6],o[7]);
    #pragma unroll
    for(int d = 0; d < 8; d++){
      float h0 = s_b2[2*d], h1 = s_b2[2*d+1];
      #pragma unroll
      for(int k = 0; k < FE; k++){
        h0 += ev[k] * s_w2[k*KH + 2*d];
        h1 += ev[k] * s_w2[k*KH + 2*d+1];
      }
      h0 = h0 > 0.f ? h0 : 0.f; h1 = h1 > 0.f ? h1 : 0.f;
      o[d] = pkh(h0, h1);
    }
    uint4* p2 = (uint4*)(hpk2 + (size_t)e*8);
    p2[0] = make_uint4(o[0],o[1],o[2],o[3]); p2[1] = make_uint4(o[4],o[5],o[6],o[7]);
    return;
  }
  {   // zero agg1+agg2 (contiguous 9.6 MB): 150000 x 64B units
    int idx = (b - MB_E)*256 + tid;
    if(idx < 150000){
      uint4 z = make_uint4(0,0,0,0);
      uint4* p = (uint4*)((char*)agg1 + (size_t)idx*64);
      p[0] = z; p[1] = z; p[2] = z; p[3] = z;
    }
  }
}

// ---- NNConv message GEMM + packed-f16 atomic scatter; conv1 carries attention-pool
// blocks (independent work co-scheduled to hide under atomic backpressure) ----
#define CONV_NB (NE/64)       // 3125
#define ATT_NB  (NG/4)        // 625 blocks x 4 waves = 2500 graphs
template<int IN, int OUT, bool AH, bool ATT>
__global__ void __launch_bounds__(256) conv_atomic_kernel(
    const void* __restrict__ nodef, const unsigned int* __restrict__ hpk,
    const int* __restrict__ ei, const unsigned short* __restrict__ wpack,
    unsigned short* __restrict__ agg,
    const float* __restrict__ gate, const float* __restrict__ xf,
    const int* __restrict__ gstart, float* __restrict__ xatt)
{
  if(ATT && blockIdx.x >= CONV_NB){
    int lane = threadIdx.x & 63, wid = threadIdx.x >> 6;
    int g = (blockIdx.x - CONV_NB)*4 + wid;
    int start = gstart[g], end = gstart[g+1];
    float mx = -1e30f;
    for(int n = start + lane; n < end; n += 64) mx = fmaxf(mx, gate[n]);
    #pragma unroll
    for(int o = 32; o >= 1; o >>= 1) mx = fmaxf(mx, __shfl_xor(mx, o));
    float s = 0.f;
    float acc[FN];
    #pragma unroll
    for(int f = 0; f < FN; f++) acc[f] = 0.f;
    for(int n = start + lane; n < end; n += 64){
      float a = __expf(gate[n] - mx);
      s += a;
      const float4* xp = (const float4*)(xf + (size_t)n * FN);
      #pragma unroll
      for(int q = 0; q < 4; q++){
        float4 v = xp[q];
        acc[q*4+0] += a*v.x; acc[q*4+1] += a*v.y; acc[q*4+2] += a*v.z; acc[q*4+3] += a*v.w;
      }
    }
    #pragma unroll
    for(int o = 32; o >= 1; o >>= 1){
      s += __shfl_xor(s, o);
      #pragma unroll
      for(int f = 0; f < FN; f++) acc[f] += __shfl_xor(acc[f], o);
    }
    if(lane < FN) xatt[(size_t)g*FN + lane] = (end > start && s > 0.f) ? acc[lane] / s : 0.f;
    return;
  }
  constexpr int KMF  = ((KH*IN + IN + 31)/32)*32;   // 288 | 544
  constexpr int KP   = KMF + 8;                     // 296 | 552
  constexpr int NT   = OUT/16;                      // 2 | 1
  constexpr int KS   = KMF/32;                      // 9 | 17
  int tid = threadIdx.x;
  int lane = tid & 63, m = lane & 15, quad = lane >> 4;
  int wid = tid >> 6;
  int ebase = blockIdx.x*64 + wid*16;
  int em = ebase + m;
  int sn = ei[em];                                  // src node
  int q1 = quad >> 1;
  int xoff = (IN == 16) ? ((quad & 1)*8) : (quad*8);
  union { half8v v; half2v h[4]; unsigned int w[4]; } X;
  if(AH){
    uint4 u = *(const uint4*)((const unsigned short*)nodef + (size_t)sn*IN + xoff);
    X.w[0]=u.x; X.w[1]=u.y; X.w[2]=u.z; X.w[3]=u.w;
  } else {
    const float4* xp = (const float4*)((const float*)nodef + (size_t)sn*IN + xoff);
    float4 v0 = xp[0], v1 = xp[1];
    X.w[0] = pkh(v0.x, v0.y);
    X.w[1] = pkh(v0.z, v0.w);
    X.w[2] = pkh(v1.x, v1.y);
    X.w[3] = pkh(v1.z, v1.w);
  }
  unsigned int hu[8];
  {
    const uint4* hp = (const uint4*)(hpk + (size_t)em*8);
    uint4 u0 = hp[0], u1 = hp[1];
    hu[0]=u0.x; hu[1]=u0.y; hu[2]=u0.z; hu[3]=u0.w;
    hu[4]=u1.x; hu[5]=u1.y; hu[6]=u1.z; hu[7]=u1.w;
  }
  int4 tg = *(const int4*)(ei + NE + ebase + quad*4);

  f32x4 acc[NT];
  #pragma unroll
  for(int nt = 0; nt < NT; nt++) acc[nt] = (f32x4){0.f,0.f,0.f,0.f};

  const half8v hz = {};
  #pragma unroll
  for(int ks = 0; ks < KS; ks++){
    union { half8v v; half2v h[4]; } A;
    if(ks < KS-1){
      unsigned short hs = (unsigned short)((IN == 16) ? (hu[ks] >> (16*q1))
                                                      : (hu[ks >> 1] >> (16*(ks & 1))));
      union { unsigned short s; _Float16 h; } hc; hc.s = hs;
      half2v hv2 = { hc.h, hc.h };
      #pragma unroll
      for(int k = 0; k < 4; k++) A.h[k] = hv2 * X.h[k];   // v_pk_mul_f16
    } else {
      if(IN == 16) A.v = (quad < 2) ? X.v : hz;
      else         A.v = X.v;
    }
    #pragma unroll
    for(int nt = 0; nt < NT; nt++){
      half8v b = *(const half8v*)(wpack + (size_t)(nt*16 + m)*KP + ks*32 + quad*8);
      acc[nt] = __builtin_amdgcn_mfma_f32_16x16x32_f16(A.v, b, acc[nt], 0, 0, 0);
    }
  }
  int tr[4] = {tg.x, tg.y, tg.z, tg.w};
  int mlo = m & ~1;
  bool evn = (m & 1) == 0;
  #pragma unroll
  for(int r = 0; r < 4; r++){
    #pragma unroll
    for(int nt = 0; nt < NT; nt++){
      float v = acc[nt][r];
      float vn = __shfl_xor(v, 1);
      if(evn ? (r < 2) : (r >= 2)){
        unsigned int pk = evn ? pkh(v, vn) : pkh(vn, v);
        atomic_pk_f16(agg + (size_t)tr[r]*OUT + nt*16 + mlo, pk);
      }
    }
  }
}

// h1 = relu(x@wr1 + br1 + agg1[n]) -> f16. 8 threads/node, pure streaming.
__global__ void __launch_bounds__(256) node1_kernel(
    const float* __restrict__ xf, const unsigned short* __restrict__ agg1,
    const float* __restrict__ wr, const float* __restrict__ br,
    unsigned short* __restrict__ h1b)
{
  __shared__ float s_w[FN*H1C], s_b[H1C];
  for(int i = threadIdx.x; i < FN*H1C; i += 256) s_w[i] = wr[i];
  if(threadIdx.x < H1C) s_b[threadIdx.x] = br[threadIdx.x];
  __syncthreads();
  int g = blockIdx.x*256 + threadIdx.x;
  int n = g >> 3, q = g & 7;
  if(n >= NN) return;
  uint2 au = *(const uint2*)(agg1 + (size_t)n*H1C + q*4);
  float a0 = s_b[q*4+0] + h2lo(au.x), a1 = s_b[q*4+1] + h2hi(au.x);
  float a2 = s_b[q*4+2] + h2lo(au.y), a3 = s_b[q*4+3] + h2hi(au.y);
  const float* xr = xf + (size_t)n*FN;
  #pragma unroll
  for(int i = 0; i < FN; i++){
    float xi = xr[i];
    a0 += xi*s_w[i*H1C + q*4+0]; a1 += xi*s_w[i*H1C + q*4+1];
    a2 += xi*s_w[i*H1C + q*4+2]; a3 += xi*s_w[i*H1C + q*4+3];
  }
  a0 = a0>0.f?a0:0.f; a1 = a1>0.f?a1:0.f; a2 = a2>0.f?a2:0.f; a3 = a3>0.f?a3:0.f;
  uint2 hb; hb.x = pkh(a0, a1); hb.y = pkh(a2, a3);
  *(uint2*)(h1b + (size_t)n*H1C + q*4) = hb;
}

// h2 = relu(h1@wr2 + br2 + agg2[n]); 4 threads/node; h1 read as f16
__global__ void __launch_bounds__(256) node2_kernel(
    const unsigned short* __restrict__ h1b, const unsigned short* __restrict__ agg2,
    const float* __restrict__ wr, const float* __restrict__ br, float* __restrict__ h2)
{
  __shared__ float s_w[H1C*H2C], s_b[H2C];
  for(int i = threadIdx.x; i < H1C*H2C; i += 256) s_w[i] = wr[i];
  if(threadIdx.x < H2C) s_b[threadIdx.x] = br[threadIdx.x];
  __syncthreads();
  int g = blockIdx.x*256 + threadIdx.x;
  int n = g >> 2, q = g & 3;
  if(n >= NN) return;
  uint2 au = *(const uint2*)(agg2 + (size_t)n*H2C + q*4);
  float a0 = s_b[q*4+0] + h2lo(au.x), a1 = s_b[q*4+1] + h2hi(au.x);
  float a2 = s_b[q*4+2] + h2lo(au.y), a3 = s_b[q*4+3] + h2hi(au.y);
  const unsigned int* hb = (const unsigned int*)(h1b + (size_t)n*H1C);
  #pragma unroll
  for(int i2 = 0; i2 < H1C/2; i2++){
    unsigned int u = hb[i2];
    float x0 = h2lo(u), x1 = h2hi(u);
    int i = 2*i2;
    a0 += x0*s_w[i*H2C + q*4+0] + x1*s_w[(i+1)*H2C + q*4+0];
    a1 += x0*s_w[i*H2C + q*4+1] + x1*s_w[(i+1)*H2C + q*4+1];
    a2 += x0*s_w[i*H2C + q*4+2] + x1*s_w[(i+1)*H2C + q*4+2];
    a3 += x0*s_w[i*H2C + q*4+3] + x1*s_w[(i+1)*H2C + q*4+3];
  }
  float4 r; r.x = a0>0.f?a0:0.f; r.y = a1>0.f?a1:0.f; r.z = a2>0.f?a2:0.f; r.w = a3>0.f?a3:0.f;
  *(float4*)(h2 + (size_t)n*H2C + q*4) = r;
}

// one wave per graph: mean-pool h2 + concat xatt + head MLP
__global__ void head_kernel(const float* __restrict__ xatt,
    const float* __restrict__ h2, const int* __restrict__ gstart, const void* __restrict__ xin,
    const float* __restrict__ wl1, const float* __restrict__ bl1,
    const float* __restrict__ wl2, const float* __restrict__ bl2,
    void* __restrict__ out)
{
  __shared__ float sz[H2C + FN];
  int g = blockIdx.x;
  int lane = threadIdx.x;
  bool isbf = detect_isbf(xin);
  int start = gstart[g];
  int end   = gstart[g + 1];
  float acc[H2C];
  #pragma unroll
  for(int f = 0; f < H2C; f++) acc[f] = 0.f;
  for(int n = start + lane; n < end; n += 64){
    const float4* hp = (const float4*)(h2 + (size_t)n*H2C);
    #pragma unroll
    for(int q = 0; q < 4; q++){
      float4 v = hp[q];
      acc[q*4+0] += v.x; acc[q*4+1] += v.y; acc[q*4+2] += v.z; acc[q*4+3] += v.w;
    }
  }
  #pragma unroll
  for(int o = 32; o >= 1; o >>= 1){
    #pragma unroll
    for(int f = 0; f < H2C; f++) acc[f] += __shfl_xor(acc[f], o);
  }
  float inv = 1.f / fmaxf((float)(end - start), 1.f);
  if(lane < H2C) sz[lane] = acc[lane] * inv;
  if(lane < FN)  sz[H2C + lane] = xatt[(size_t)g*FN + lane];
  __syncthreads();
  if(lane == 0){
    float t1[8];
    #pragma unroll
    for(int j = 0; j < 8; j++){
      float t = bl1[j];
      #pragma unroll
      for(int c = 0; c < H2C + FN; c++) t += sz[c] * wl1[c*8 + j];
      t1[j] = t;
    }
    float o = bl2[0];
    #pragma unroll
    for(int j = 0; j < 8; j++) o += t1[j] * wl2[j];
    if(isbf) ((__hip_bfloat16*)out)[g] = __float2bfloat16(o);
    else     ((float*)out)[g] = o;
  }
}

extern "C" void kernel_launch(void* const* d_in, const int* in_sizes, int n_in,
                              void* d_out, int out_size, void* d_ws, size_t ws_size,
                              hipStream_t stream)
{
  const int* ei    = (const int*)d_in[22];
  const int* batch = (const int*)d_in[23];

  float* ws = (float*)d_ws;
  float* xf     = ws;                          // 1,600,000 f
  float* gate   = xf + 1600000;                //   100,000 f
  float* wts    = gate + 100000;               //    19,360 f
  float* xatt   = wts + 19360;                 //    40,000 f
  int*   gstart = (int*)(xatt + 40000);        //     2,504 i
  unsigned int* wpack1 = (unsigned int*)(gstart + 2504);   // 4,736 u32
  unsigned int* wpack2 = wpack1 + 4736;                    // 4,416 u32
  unsigned int* hpk1   = wpack2 + 4416;        // 1,600,000 u32 ([NE][8])
  unsigned int* hpk2   = hpk1 + 1600000;       // 1,600,000 u32
  unsigned short* h1b  = (unsigned short*)(hpk2 + 1600000); // 3,200,000 u16
  float* h2     = (float*)(h1b + 3200000);     // 1,600,000 f
  unsigned short* agg1 = (unsigned short*)(h2 + 1600000);   // 3,200,000 u16 (zeroed in mega1)
  unsigned short* agg2 = agg1 + 3200000;       // 1,600,000 u16 (contiguous with agg1)
  // total ~42 MB

  WArgs wa;
  for(int i = 0; i < NW; i++) wa.p[i] = d_in[2 + i];

  mega1_kernel<<<MB_F, 256, 0, stream>>>(d_in[0], d_in[1], wa, batch,
      wts, wpack1, wpack2, gate, xf, hpk1, hpk2, gstart, agg1);

  conv_atomic_kernel<FN, H1C, false, true><<<CONV_NB + ATT_NB, 256, 0, stream>>>(
      xf, hpk1, ei, (const unsigned short*)wpack1, agg1, gate, xf, gstart, xatt);
  node1_kernel<<<(NN*8 + 255)/256, 256, 0, stream>>>(xf, agg1, wts+OW_R1, wts+OB_R1, h1b);

  conv_atomic_kernel<H1C, H2C, true, false><<<CONV_NB, 256, 0, stream>>>(
      h1b, hpk2, ei, (const unsigned short*)wpack2, agg2, gate, xf, gstart, xatt);
  node2_kernel<<<(NN*4 + 255)/256, 256, 0, stream>>>(h1b, agg2, wts+OW_R2, wts+OB_R2, h2);

  head_kernel<<<NG, 64, 0, stream>>>(xatt, h2, gstart, d_in[0],
      wts+OW_L1, wts+OB_L1, wts+OW_L2, wts+OB_L2, d_out);
}

// Round 9
// 184.984 us; speedup vs baseline: 1.1642x; 1.0100x over previous
//
#include <hip/hip_runtime.h>
#include <hip/hip_bf16.h>

#define NN 100000   // nodes
#define NE 200000   // edges
#define NG 2500     // graphs
#define FN 16       // node feats
#define FE 8        // edge feats
#define H1C 32
#define H2C 16
#define KH 16       // edge-MLP hidden

typedef __attribute__((ext_vector_type(4))) float f32x4;
typedef _Float16 __attribute__((ext_vector_type(2))) half2v;
typedef _Float16 __attribute__((ext_vector_type(8))) half8v;
typedef __fp16 __attribute__((ext_vector_type(2))) pkf16x2;   // cvt_pkrtz result type

__device__ __forceinline__ float bf2f(unsigned int u){
  union { unsigned int i; float f; } v; v.i = (u & 0xffffu) << 16; return v.f;
}
__device__ __forceinline__ unsigned int pkh(float a, float b){
  union { pkf16x2 h; unsigned int u; } v; v.h = __builtin_amdgcn_cvt_pkrtz(a, b); return v.u;
}
__device__ __forceinline__ float h2lo(unsigned int u){
  union { unsigned short s; _Float16 h; } v; v.s = (unsigned short)u; return (float)v.h;
}
__device__ __forceinline__ float h2hi(unsigned int u){
  union { unsigned short s; _Float16 h; } v; v.s = (unsigned short)(u >> 16); return (float)v.h;
}
__device__ __forceinline__ float rdf(const void* p, long i, bool isbf){
  return isbf ? bf2f(((const unsigned short*)p)[i]) : ((const float*)p)[i];
}
// fire-and-forget packed-f16 atomic add (2 values / op)
__device__ __forceinline__ void atomic_pk_f16(unsigned short* addr, unsigned int pk){
  asm volatile("global_atomic_pk_add_f16 %0, %1, off" :: "v"(addr), "v"(pk) : "memory");
}
// inline dtype detection: wave-ballot over 64 sampled halfwords of x
__device__ __forceinline__ bool detect_isbf(const void* __restrict__ x){
  const unsigned short* u = (const unsigned short*)x;
  int lane = threadIdx.x & 63;
  float f = bf2f(u[2*lane]);
  float a = fabsf(f);
  bool sane = (f == 0.0f) || (a > 1e-4f && a < 1e4f);
  unsigned long long b = __ballot(sane);
  return __popcll(b) >= 32;
}
// load node-row x[n] (16 feats) from raw input, exact conversion
__device__ __forceinline__ void load_x16(const void* __restrict__ xin, bool isbf, int n, float* xv){
  if(isbf){
    uint4 u0 = ((const uint4*)xin)[2*n], u1 = ((const uint4*)xin)[2*n+1];
    xv[0]=bf2f(u0.x); xv[1]=bf2f(u0.x>>16); xv[2]=bf2f(u0.y); xv[3]=bf2f(u0.y>>16);
    xv[4]=bf2f(u0.z); xv[5]=bf2f(u0.z>>16); xv[6]=bf2f(u0.w); xv[7]=bf2f(u0.w>>16);
    xv[8]=bf2f(u1.x); xv[9]=bf2f(u1.x>>16); xv[10]=bf2f(u1.y); xv[11]=bf2f(u1.y>>16);
    xv[12]=bf2f(u1.z); xv[13]=bf2f(u1.z>>16); xv[14]=bf2f(u1.w); xv[15]=bf2f(u1.w>>16);
  } else {
    #pragma unroll
    for(int q = 0; q < 4; q++){
      float4 v = ((const float4*)xin)[4*n + q];
      xv[q*4+0]=v.x; xv[q*4+1]=v.y; xv[q*4+2]=v.z; xv[q*4+3]=v.w;
    }
  }
}

#define NW 20
struct WArgs { const void* p[NW]; };
enum {
  OW_E1A=0,     OB_E1A=128,   OW_E1B=144,   OB_E1B=8336,  OW_R1=8848,  OB_R1=9360,
  OW_E2A=9392,  OB_E2A=9520,  OW_E2B=9536,  OB_E2B=17728, OW_R2=18240, OB_R2=18752,
  OW_G1=18768,  OB_G1=19024,  OW_G2=19040,  OB_G2=19056,
  OW_L1=19057,  OB_L1=19313,  OW_L2=19321,  OB_L2=19329
};

// ---- conv tile: message GEMM + packed-f16 atomic scatter ----
// RAWX: conv1 reads raw x (bf16/f32, inline cvt); else conv2 reads f16-packed h1b.
template<int IN, int OUT, bool RAWX>
__device__ __forceinline__ void conv_tile(
    int u, const void* __restrict__ nodef, bool isbf,
    const unsigned int* __restrict__ hpk, const int* __restrict__ ei,
    const unsigned short* __restrict__ wpack, unsigned short* __restrict__ agg)
{
  constexpr int KMF  = ((KH*IN + IN + 31)/32)*32;   // 288 | 544
  constexpr int KP   = KMF + 8;                     // 296 | 552
  constexpr int NT   = OUT/16;                      // 2 | 1
  constexpr int KS   = KMF/32;                      // 9 | 17
  int tid = threadIdx.x;
  int lane = tid & 63, m = lane & 15, quad = lane >> 4;
  int wid = tid >> 6;
  int ebase = u*64 + wid*16;
  int em = ebase + m;
  int sn = ei[em];                                  // src node
  int q1 = quad >> 1;
  int xoff = (IN == 16) ? ((quad & 1)*8) : (quad*8);
  union { half8v v; half2v h[4]; unsigned int w[4]; } X;
  if(RAWX){
    if(isbf){
      uint4 uu = *(const uint4*)((const unsigned short*)nodef + (size_t)sn*IN + xoff);
      X.w[0] = pkh(bf2f(uu.x), bf2f(uu.x >> 16));
      X.w[1] = pkh(bf2f(uu.y), bf2f(uu.y >> 16));
      X.w[2] = pkh(bf2f(uu.z), bf2f(uu.z >> 16));
      X.w[3] = pkh(bf2f(uu.w), bf2f(uu.w >> 16));
    } else {
      const float4* xp = (const float4*)((const float*)nodef + (size_t)sn*IN + xoff);
      float4 v0 = xp[0], v1 = xp[1];
      X.w[0] = pkh(v0.x, v0.y);
      X.w[1] = pkh(v0.z, v0.w);
      X.w[2] = pkh(v1.x, v1.y);
      X.w[3] = pkh(v1.z, v1.w);
    }
  } else {
    uint4 uu = *(const uint4*)((const unsigned short*)nodef + (size_t)sn*IN + xoff);
    X.w[0]=uu.x; X.w[1]=uu.y; X.w[2]=uu.z; X.w[3]=uu.w;
  }
  unsigned int hu[8];
  {
    const uint4* hp = (const uint4*)(hpk + (size_t)em*8);
    uint4 u0 = hp[0], u1 = hp[1];
    hu[0]=u0.x; hu[1]=u0.y; hu[2]=u0.z; hu[3]=u0.w;
    hu[4]=u1.x; hu[5]=u1.y; hu[6]=u1.z; hu[7]=u1.w;
  }
  int4 tg = *(const int4*)(ei + NE + ebase + quad*4);

  f32x4 acc[NT];
  #pragma unroll
  for(int nt = 0; nt < NT; nt++) acc[nt] = (f32x4){0.f,0.f,0.f,0.f};

  const half8v hz = {};
  #pragma unroll
  for(int ks = 0; ks < KS; ks++){
    union { half8v v; half2v h[4]; } A;
    if(ks < KS-1){
      unsigned short hs = (unsigned short)((IN == 16) ? (hu[ks] >> (16*q1))
                                                      : (hu[ks >> 1] >> (16*(ks & 1))));
      union { unsigned short s; _Float16 h; } hc; hc.s = hs;
      half2v hv2 = { hc.h, hc.h };
      #pragma unroll
      for(int k = 0; k < 4; k++) A.h[k] = hv2 * X.h[k];   // v_pk_mul_f16
    } else {
      if(IN == 16) A.v = (quad < 2) ? X.v : hz;
      else         A.v = X.v;
    }
    #pragma unroll
    for(int nt = 0; nt < NT; nt++){
      half8v b = *(const half8v*)(wpack + (size_t)(nt*16 + m)*KP + ks*32 + quad*8);
      acc[nt] = __builtin_amdgcn_mfma_f32_16x16x32_f16(A.v, b, acc[nt], 0, 0, 0);
    }
  }
  int tr[4] = {tg.x, tg.y, tg.z, tg.w};
  int mlo = m & ~1;
  bool evn = (m & 1) == 0;
  #pragma unroll
  for(int r = 0; r < 4; r++){
    #pragma unroll
    for(int nt = 0; nt < NT; nt++){
      float v = acc[nt][r];
      float vn = __shfl_xor(v, 1);
      if(evn ? (r < 2) : (r >= 2)){
        unsigned int pk = evn ? pkh(v, vn) : pkh(vn, v);
        atomic_pk_f16(agg + (size_t)tr[r]*OUT + nt*16 + mlo, pk);
      }
    }
  }
}

// ---- mega setup: wts-cvt | wpack1 | wpack2 | gate+gstart | edge-MLP1 | agg1-zero ----
#define MB_A 76               // wts cvt: 19330 elems
#define MB_B (MB_A + 19)      // wpack1: 4736
#define MB_C (MB_B + 18)      // wpack2: 4416
#define MB_D (MB_C + 391)     // gate+gstart: NN
#define MB_E (MB_D + 782)     // edge-MLP1: NE
#define MB_F (MB_E + 391)     // agg1 zero: 100000 x 64B
__global__ void __launch_bounds__(256) mega1_kernel(
    const void* __restrict__ xin, const void* __restrict__ efin, WArgs w,
    const int* __restrict__ batch,
    float* __restrict__ wts, unsigned int* __restrict__ wpack1, unsigned int* __restrict__ wpack2,
    float* __restrict__ gate,
    unsigned int* __restrict__ hpk1,
    int* __restrict__ gstart, unsigned short* __restrict__ agg1)
{
  int b = blockIdx.x, tid = threadIdx.x;
  if(b < MB_A){
    bool isbf = detect_isbf(xin);
    int i = b*256 + tid;
    if(i >= 19330) return;
    const int sz[NW] = {128,16,8192,512,512,32, 128,16,8192,512,512,16, 256,16,16,1, 256,8,8,1};
    int seg = 0; long base = 0;
    while(i - base >= sz[seg]){ base += sz[seg]; seg++; }
    wts[i] = rdf(w.p[seg], i - base, isbf);
    return;
  }
  if(b < MB_B){   // wpack1: 32 rows x 148 u32 (KP=296), f16 payload
    bool isbf = detect_isbf(xin);
    int j = (b - MB_A)*256 + tid;
    if(j >= 4736) return;
    int n = j / 148; int k = (j % 148) * 2;
    float v0 = 0.f, v1 = 0.f;
    if(k < 256)        v0 = rdf(w.p[2], (long)k*32 + n, isbf);
    else if(k < 272)   v0 = rdf(w.p[3], (long)(k-256)*32 + n, isbf);
    if(k+1 < 256)      v1 = rdf(w.p[2], (long)(k+1)*32 + n, isbf);
    else if(k+1 < 272) v1 = rdf(w.p[3], (long)(k+1-256)*32 + n, isbf);
    wpack1[j] = pkh(v0, v1);
    return;
  }
  if(b < MB_C){   // wpack2: 16 rows x 276 u32 (KP=552), f16 payload
    bool isbf = detect_isbf(xin);
    int j = (b - MB_B)*256 + tid;
    if(j >= 4416) return;
    int n = j / 276; int k = (j % 276) * 2;
    float v0 = 0.f, v1 = 0.f;
    if(k < 512)        v0 = rdf(w.p[8], (long)k*16 + n, isbf);
    else if(k < 544)   v0 = rdf(w.p[9], (long)(k-512)*16 + n, isbf);
    if(k+1 < 512)      v1 = rdf(w.p[8], (long)(k+1)*16 + n, isbf);
    else if(k+1 < 544) v1 = rdf(w.p[9], (long)(k+1-512)*16 + n, isbf);
    wpack2[j] = pkh(v0, v1);
    return;
  }
  if(b < MB_D){   // gate MLP + gstart table (reads raw x; no xf mirror)
    __shared__ float s_w1[FN*FN], s_b1[FN], s_w2[FN], s_b2v[1];
    bool isbf = detect_isbf(xin);
    if(tid < FN*FN) s_w1[tid] = rdf(w.p[12], tid, isbf);
    if(tid < FN){ s_b1[tid] = rdf(w.p[13], tid, isbf); s_w2[tid] = rdf(w.p[14], tid, isbf); }
    if(tid == 0) s_b2v[0] = rdf(w.p[15], 0, isbf);
    __syncthreads();
    int n = (b - MB_C)*256 + tid;
    if(n >= NN) return;
    {
      int b1 = batch[n];
      int b0 = (n == 0) ? -1 : batch[n-1];
      for(int g2 = b0 + 1; g2 <= b1; g2++) gstart[g2] = n;
      if(n == NN-1) for(int g2 = b1 + 1; g2 <= NG; g2++) gstart[g2] = NN;
    }
    float xv[FN];
    load_x16(xin, isbf, n, xv);
    float g = s_b2v[0];
    #pragma unroll
    for(int j = 0; j < FN; j++){
      float hj = s_b1[j];
      #pragma unroll
      for(int i = 0; i < FN; i++) hj += xv[i] * s_w1[i*FN + j];
      hj = hj > 0.f ? hj : 0.f;
      g += hj * s_w2[j];
    }
    gate[n] = g;
    return;
  }
  if(b < MB_E){   // edge-MLP1: per-edge conv1 hidden vector, f16-packed, original order
    __shared__ float s_w1[FE*KH], s_b1[KH];
    bool isbf = detect_isbf(xin);
    if(tid < FE*KH) s_w1[tid] = rdf(w.p[0], tid, isbf);
    if(tid < KH) s_b1[tid] = rdf(w.p[1], tid, isbf);
    __syncthreads();
    int e = (b - MB_D)*256 + tid;
    if(e >= NE) return;
    float ev[FE];
    if(isbf){
      uint4 u = ((const uint4*)efin)[e];
      ev[0]=bf2f(u.x); ev[1]=bf2f(u.x>>16); ev[2]=bf2f(u.y); ev[3]=bf2f(u.y>>16);
      ev[4]=bf2f(u.z); ev[5]=bf2f(u.z>>16); ev[6]=bf2f(u.w); ev[7]=bf2f(u.w>>16);
    } else {
      float4 a = ((const float4*)efin)[2*e], bb = ((const float4*)efin)[2*e+1];
      ev[0]=a.x; ev[1]=a.y; ev[2]=a.z; ev[3]=a.w; ev[4]=bb.x; ev[5]=bb.y; ev[6]=bb.z; ev[7]=bb.w;
    }
    unsigned int o[8];
    #pragma unroll
    for(int d = 0; d < 8; d++){
      float h0 = s_b1[2*d], h1 = s_b1[2*d+1];
      #pragma unroll
      for(int k = 0; k < FE; k++){
        h0 += ev[k] * s_w1[k*KH + 2*d];
        h1 += ev[k] * s_w1[k*KH + 2*d+1];
      }
      h0 = h0 > 0.f ? h0 : 0.f; h1 = h1 > 0.f ? h1 : 0.f;
      o[d] = pkh(h0, h1);
    }
    uint4* p1 = (uint4*)(hpk1 + (size_t)e*8);
    p1[0] = make_uint4(o[0],o[1],o[2],o[3]); p1[1] = make_uint4(o[4],o[5],o[6],o[7]);
    return;
  }
  {   // zero agg1 (6.4 MB): 100000 x 64B units
    int idx = (b - MB_E)*256 + tid;
    if(idx < 100000){
      uint4 z = make_uint4(0,0,0,0);
      uint4* p = (uint4*)((char*)agg1 + (size_t)idx*64);
      p[0] = z; p[1] = z; p[2] = z; p[3] = z;
    }
  }
}

// ---- conv1 launch: conv tiles | edge-MLP2 | agg2-zero | attention pool ----
// Trailing segments are independent of the conv tiles (consumed only after the next
// kernel boundary) and ride in conv1's atomic-idle VALU/BW capacity.
#define C1_CONV (NE/64)           // 3125
#define C1_E2   (C1_CONV + 782)   // edge-MLP2: NE
#define C1_Z    (C1_E2 + 196)     // agg2 zero: 50000 x 64B
#define C1_ATT  (C1_Z + 625)      // attention: NG/4 blocks x 4 waves
__global__ void __launch_bounds__(256) conv1_kernel(
    const void* __restrict__ xin, const void* __restrict__ efin,
    const float* __restrict__ wts,
    const unsigned int* __restrict__ hpk1, const int* __restrict__ ei,
    const unsigned short* __restrict__ wpack1,
    unsigned short* __restrict__ agg1, unsigned short* __restrict__ agg2,
    unsigned int* __restrict__ hpk2,
    const float* __restrict__ gate, const int* __restrict__ gstart,
    float* __restrict__ xatt)
{
  int b = blockIdx.x, tid = threadIdx.x;
  bool isbf = detect_isbf(xin);
  if(b < C1_CONV){
    conv_tile<FN, H1C, true>(b, xin, isbf, hpk1, ei, wpack1, agg1);
    return;
  }
  if(b < C1_E2){   // edge-MLP2 -> hpk2 (weights from converted wts; mega1 boundary passed)
    __shared__ float s_w2[FE*KH], s_b2[KH];
    if(tid < FE*KH) s_w2[tid] = wts[OW_E2A + tid];
    if(tid < KH) s_b2[tid] = wts[OB_E2A + tid];
    __syncthreads();
    int e = (b - C1_CONV)*256 + tid;
    if(e >= NE) return;
    float ev[FE];
    if(isbf){
      uint4 u = ((const uint4*)efin)[e];
      ev[0]=bf2f(u.x); ev[1]=bf2f(u.x>>16); ev[2]=bf2f(u.y); ev[3]=bf2f(u.y>>16);
      ev[4]=bf2f(u.z); ev[5]=bf2f(u.z>>16); ev[6]=bf2f(u.w); ev[7]=bf2f(u.w>>16);
    } else {
      float4 a = ((const float4*)efin)[2*e], bb = ((const float4*)efin)[2*e+1];
      ev[0]=a.x; ev[1]=a.y; ev[2]=a.z; ev[3]=a.w; ev[4]=bb.x; ev[5]=bb.y; ev[6]=bb.z; ev[7]=bb.w;
    }
    unsigned int o[8];
    #pragma unroll
    for(int d = 0; d < 8; d++){
      float h0 = s_b2[2*d], h1 = s_b2[2*d+1];
      #pragma unroll
      for(int k = 0; k < FE; k++){
        h0 += ev[k] * s_w2[k*KH + 2*d];
        h1 += ev[k] * s_w2[k*KH + 2*d+1];
      }
      h0 = h0 > 0.f ? h0 : 0.f; h1 = h1 > 0.f ? h1 : 0.f;
      o[d] = pkh(h0, h1);
    }
    uint4* p2 = (uint4*)(hpk2 + (size_t)e*8);
    p2[0] = make_uint4(o[0],o[1],o[2],o[3]); p2[1] = make_uint4(o[4],o[5],o[6],o[7]);
    return;
  }
  if(b < C1_Z){    // zero agg2 (3.2 MB): 50000 x 64B units
    int idx = (b - C1_E2)*256 + tid;
    if(idx < 50000){
      uint4 z = make_uint4(0,0,0,0);
      uint4* p = (uint4*)((char*)agg2 + (size_t)idx*64);
      p[0] = z; p[1] = z; p[2] = z; p[3] = z;
    }
    return;
  }
  {   // attention pool: 4 waves/block, one graph per wave, raw x reads
    int lane = tid & 63, wid = tid >> 6;
    int g = (b - C1_Z)*4 + wid;
    int start = gstart[g], end = gstart[g+1];
    float mx = -1e30f;
    for(int n = start + lane; n < end; n += 64) mx = fmaxf(mx, gate[n]);
    #pragma unroll
    for(int o = 32; o >= 1; o >>= 1) mx = fmaxf(mx, __shfl_xor(mx, o));
    float s = 0.f;
    float acc[FN];
    #pragma unroll
    for(int f = 0; f < FN; f++) acc[f] = 0.f;
    for(int n = start + lane; n < end; n += 64){
      float a = __expf(gate[n] - mx);
      s += a;
      float xv[FN];
      load_x16(xin, isbf, n, xv);
      #pragma unroll
      for(int f = 0; f < FN; f++) acc[f] += a * xv[f];
    }
    #pragma unroll
    for(int o = 32; o >= 1; o >>= 1){
      s += __shfl_xor(s, o);
      #pragma unroll
      for(int f = 0; f < FN; f++) acc[f] += __shfl_xor(acc[f], o);
    }
    if(lane < FN) xatt[(size_t)g*FN + lane] = (end > start && s > 0.f) ? acc[lane] / s : 0.f;
  }
}

// ---- conv2: plain conv tiles (h1b node feats) ----
__global__ void __launch_bounds__(256) conv2_kernel(
    const unsigned short* __restrict__ h1b, const unsigned int* __restrict__ hpk2,
    const int* __restrict__ ei, const unsigned short* __restrict__ wpack2,
    unsigned short* __restrict__ agg2)
{
  conv_tile<H1C, H2C, false>(blockIdx.x, h1b, false, hpk2, ei, wpack2, agg2);
}

// h1 = relu(x@wr1 + br1 + agg1[n]) -> f16. 8 threads/node; raw-x root term.
__global__ void __launch_bounds__(256) node1_kernel(
    const void* __restrict__ xin, const unsigned short* __restrict__ agg1,
    const float* __restrict__ wr, const float* __restrict__ br,
    unsigned short* __restrict__ h1b)
{
  __shared__ float s_w[FN*H1C], s_b[H1C];
  for(int i = threadIdx.x; i < FN*H1C; i += 256) s_w[i] = wr[i];
  if(threadIdx.x < H1C) s_b[threadIdx.x] = br[threadIdx.x];
  bool isbf = detect_isbf(xin);
  __syncthreads();
  int g = blockIdx.x*256 + threadIdx.x;
  int n = g >> 3, q = g & 7;
  if(n >= NN) return;
  uint2 au = *(const uint2*)(agg1 + (size_t)n*H1C + q*4);
  float a0 = s_b[q*4+0] + h2lo(au.x), a1 = s_b[q*4+1] + h2hi(au.x);
  float a2 = s_b[q*4+2] + h2lo(au.y), a3 = s_b[q*4+3] + h2hi(au.y);
  float xv[FN];
  load_x16(xin, isbf, n, xv);
  #pragma unroll
  for(int i = 0; i < FN; i++){
    float xi = xv[i];
    a0 += xi*s_w[i*H1C + q*4+0]; a1 += xi*s_w[i*H1C + q*4+1];
    a2 += xi*s_w[i*H1C + q*4+2]; a3 += xi*s_w[i*H1C + q*4+3];
  }
  a0 = a0>0.f?a0:0.f; a1 = a1>0.f?a1:0.f; a2 = a2>0.f?a2:0.f; a3 = a3>0.f?a3:0.f;
  uint2 hb; hb.x = pkh(a0, a1); hb.y = pkh(a2, a3);
  *(uint2*)(h1b + (size_t)n*H1C + q*4) = hb;
}

// h2 = relu(h1@wr2 + br2 + agg2[n]); 4 threads/node; h1 read as f16
__global__ void __launch_bounds__(256) node2_kernel(
    const unsigned short* __restrict__ h1b, const unsigned short* __restrict__ agg2,
    const float* __restrict__ wr, const float* __restrict__ br, float* __restrict__ h2)
{
  __shared__ float s_w[H1C*H2C], s_b[H2C];
  for(int i = threadIdx.x; i < H1C*H2C; i += 256) s_w[i] = wr[i];
  if(threadIdx.x < H2C) s_b[threadIdx.x] = br[threadIdx.x];
  __syncthreads();
  int g = blockIdx.x*256 + threadIdx.x;
  int n = g >> 2, q = g & 3;
  if(n >= NN) return;
  uint2 au = *(const uint2*)(agg2 + (size_t)n*H2C + q*4);
  float a0 = s_b[q*4+0] + h2lo(au.x), a1 = s_b[q*4+1] + h2hi(au.x);
  float a2 = s_b[q*4+2] + h2lo(au.y), a3 = s_b[q*4+3] + h2hi(au.y);
  const unsigned int* hb = (const unsigned int*)(h1b + (size_t)n*H1C);
  #pragma unroll
  for(int i2 = 0; i2 < H1C/2; i2++){
    unsigned int u = hb[i2];
    float x0 = h2lo(u), x1 = h2hi(u);
    int i = 2*i2;
    a0 += x0*s_w[i*H2C + q*4+0] + x1*s_w[(i+1)*H2C + q*4+0];
    a1 += x0*s_w[i*H2C + q*4+1] + x1*s_w[(i+1)*H2C + q*4+1];
    a2 += x0*s_w[i*H2C + q*4+2] + x1*s_w[(i+1)*H2C + q*4+2];
    a3 += x0*s_w[i*H2C + q*4+3] + x1*s_w[(i+1)*H2C + q*4+3];
  }
  float4 r; r.x = a0>0.f?a0:0.f; r.y = a1>0.f?a1:0.f; r.z = a2>0.f?a2:0.f; r.w = a3>0.f?a3:0.f;
  *(float4*)(h2 + (size_t)n*H2C + q*4) = r;
}

// one wave per graph: mean-pool h2 + concat xatt + head MLP
__global__ void head_kernel(const float* __restrict__ xatt,
    const float* __restrict__ h2, const int* __restrict__ gstart, const void* __restrict__ xin,
    const float* __restrict__ wl1, const float* __restrict__ bl1,
    const float* __restrict__ wl2, const float* __restrict__ bl2,
    void* __restrict__ out)
{
  __shared__ float sz[H2C + FN];
  int g = blockIdx.x;
  int lane = threadIdx.x;
  bool isbf = detect_isbf(xin);
  int start = gstart[g];
  int end   = gstart[g + 1];
  float acc[H2C];
  #pragma unroll
  for(int f = 0; f < H2C; f++) acc[f] = 0.f;
  for(int n = start + lane; n < end; n += 64){
    const float4* hp = (const float4*)(h2 + (size_t)n*H2C);
    #pragma unroll
    for(int q = 0; q < 4; q++){
      float4 v = hp[q];
      acc[q*4+0] += v.x; acc[q*4+1] += v.y; acc[q*4+2] += v.z; acc[q*4+3] += v.w;
    }
  }
  #pragma unroll
  for(int o = 32; o >= 1; o >>= 1){
    #pragma unroll
    for(int f = 0; f < H2C; f++) acc[f] += __shfl_xor(acc[f], o);
  }
  float inv = 1.f / fmaxf((float)(end - start), 1.f);
  if(lane < H2C) sz[lane] = acc[lane] * inv;
  if(lane < FN)  sz[H2C + lane] = xatt[(size_t)g*FN + lane];
  __syncthreads();
  if(lane == 0){
    float t1[8];
    #pragma unroll
    for(int j = 0; j < 8; j++){
      float t = bl1[j];
      #pragma unroll
      for(int c = 0; c < H2C + FN; c++) t += sz[c] * wl1[c*8 + j];
      t1[j] = t;
    }
    float o = bl2[0];
    #pragma unroll
    for(int j = 0; j < 8; j++) o += t1[j] * wl2[j];
    if(isbf) ((__hip_bfloat16*)out)[g] = __float2bfloat16(o);
    else     ((float*)out)[g] = o;
  }
}

extern "C" void kernel_launch(void* const* d_in, const int* in_sizes, int n_in,
                              void* d_out, int out_size, void* d_ws, size_t ws_size,
                              hipStream_t stream)
{
  const int* ei    = (const int*)d_in[22];
  const int* batch = (const int*)d_in[23];

  float* ws = (float*)d_ws;
  float* gate   = ws;                          //   100,000 f
  float* wts    = gate + 100000;               //    19,360 f
  float* xatt   = wts + 19360;                 //    40,000 f
  int*   gstart = (int*)(xatt + 40000);        //     2,504 i
  unsigned int* wpack1 = (unsigned int*)(gstart + 2504);   // 4,736 u32
  unsigned int* wpack2 = wpack1 + 4736;                    // 4,416 u32
  unsigned int* hpk1   = wpack2 + 4416;        // 1,600,000 u32 ([NE][8])
  unsigned int* hpk2   = hpk1 + 1600000;       // 1,600,000 u32
  unsigned short* h1b  = (unsigned short*)(hpk2 + 1600000); // 3,200,000 u16
  float* h2     = (float*)(h1b + 3200000);     // 1,600,000 f
  unsigned short* agg1 = (unsigned short*)(h2 + 1600000);   // 3,200,000 u16 (zeroed in mega1)
  unsigned short* agg2 = agg1 + 3200000;       // 1,600,000 u16 (zeroed in conv1 launch)
  // total ~36 MB

  WArgs wa;
  for(int i = 0; i < NW; i++) wa.p[i] = d_in[2 + i];

  mega1_kernel<<<MB_F, 256, 0, stream>>>(d_in[0], d_in[1], wa, batch,
      wts, wpack1, wpack2, gate, hpk1, gstart, agg1);

  conv1_kernel<<<C1_ATT, 256, 0, stream>>>(d_in[0], d_in[1], wts, hpk1, ei,
      (const unsigned short*)wpack1, agg1, agg2, hpk2, gate, gstart, xatt);
  node1_kernel<<<(NN*8 + 255)/256, 256, 0, stream>>>(d_in[0], agg1, wts+OW_R1, wts+OB_R1, h1b);

  conv2_kernel<<<NE/64, 256, 0, stream>>>(h1b, hpk2, ei,
      (const unsigned short*)wpack2, agg2);
  node2_kernel<<<(NN*4 + 255)/256, 256, 0, stream>>>(h1b, agg2, wts+OW_R2, wts+OB_R2, h2);

  head_kernel<<<NG, 64, 0, stream>>>(xatt, h2, gstart, d_in[0],
      wts+OW_L1, wts+OB_L1, wts+OW_L2, wts+OB_L2, d_out);
}